// Round 13
// baseline (138.153 us; speedup 1.0000x reference)
//
#include <hip/hip_runtime.h>
#include <hip/hip_bf16.h>
#include <math.h>

// Problem constants
#define NB 8
#define LN 4096       // sequence length L
#define NH 8
#define NE 64
#define NC 512        // NH*NE channels
#define NM 64         // modes kept
#define LMASK 4095

typedef short s16x8 __attribute__((ext_vector_type(8)));
typedef float f32x4 __attribute__((ext_vector_type(4)));
typedef const __attribute__((address_space(1))) void gv_t;
typedef __attribute__((address_space(3))) void lv_t;

// ws layout (in floats):
//  egf : bf16[128kc][8mt][64][8]        @ 0        (1 MB)  fwd twiddle A-fragments
//  tf  : bf16[4kk][256lt][64][8]        @ 262144   (1 MB)  inv twiddle B-fragments
//  gf  : bf16[8b][4kk][32ct][64][8]     @ 524288   (1 MB)  mixed-spectrum A-fragments
//  xp  : f32[8ks][8b][8h][64i][128m±]   @ 786432   (16 MB) partial fwd GEMM outputs
//  xs  : f32[8b][8h][64i][128m±]        @ 4980736  (2 MB)  ks-summed spectrum
//  xp2 : f32 scratch for diagnostics    @ 5505024  (16 MB)
#define WS_EGF 0
#define WS_TF  262144
#define WS_GF  524288
#define WS_XP  786432
#define WS_XS  4980736
#define WS_XP2 5505024

static __device__ __forceinline__ unsigned short bf16bits(float f) {
    __hip_bfloat16 b = __float2bfloat16(f);
    return *reinterpret_cast<unsigned short*>(&b);
}

// Both twiddle tables in one launch. Blocks 0..255: egf (fwd A-frags);
// blocks 256..511: tf (inv B-frags).
__global__ __launch_bounds__(256) void k_tables(unsigned short* __restrict__ egf,
                                                unsigned short* __restrict__ tfp) {
    const int bid = blockIdx.x;
    const int s = (bid & 255) * 256 + threadIdx.x;   // 0..65535
    const int lane = s & 63;
    unsigned short v[8];
    if (bid < 256) {
        // E[2m][l]=cos, E[2m+1][l]=-sin ; slot s=(kc<<9)|(mt<<6)|lane
        int mt = (s >> 6) & 7, kc = s >> 9;
        int r = lane & 15, kg = lane >> 4;
        int mpm = mt * 16 + r;
        int m = mpm >> 1, isim = mpm & 1;
        #pragma unroll
        for (int j = 0; j < 8; ++j) {
            int l = kc * 32 + kg * 8 + j;
            int tw = (m * l) & LMASK;
            float ang = (6.283185307179586f / 4096.0f) * (float)tw;
            v[j] = bf16bits(isim ? -sinf(ang) : cosf(ang));
        }
    } else {
        // T[l][2m]=cos, T[l][2m+1]=sin ; slot s=(kk<<14)|(lt<<6)|lane
        int lt = (s >> 6) & 255, kk = s >> 14;
        int l = lt * 16 + (lane & 15);
        int khi = (lane >> 4) * 8;
        #pragma unroll
        for (int j = 0; j < 8; ++j) {
            int mp = kk * 32 + khi + j;
            int m = mp >> 1;
            int tw = (m * l) & LMASK;
            float ang = (6.283185307179586f / 4096.0f) * (float)tw;
            v[j] = bf16bits((mp & 1) ? sinf(ang) : cosf(ang));
        }
    }
    uint4 pk;
    pk.x = (unsigned)v[0] | ((unsigned)v[1] << 16);
    pk.y = (unsigned)v[2] | ((unsigned)v[3] << 16);
    pk.z = (unsigned)v[4] | ((unsigned)v[5] << 16);
    pk.w = (unsigned)v[6] | ((unsigned)v[7] << 16);
    unsigned short* dst = (bid < 256) ? egf : tfp;
    *reinterpret_cast<uint4*>(dst + (size_t)s * 8) = pk;
}

// Fused stage 1 (v6, round-10 verbatim = best measured config).
__global__ __launch_bounds__(256, 2) void k_fs1(const float* __restrict__ q,
                                                const unsigned short* __restrict__ egf,
                                                float* __restrict__ xp) {
    __shared__ float qlds[4][4][32][16];        // 32 KB: [slot][wave][l][i]
    __shared__ unsigned short eglds[4][4096];   // 32 KB: [slot][frag bytes of one kc]
    const int ks = blockIdx.x, h = blockIdx.y, b = blockIdx.z;
    const int tid = threadIdx.x;
    const int w = tid >> 6, lane = tid & 63;
    const int g = lane >> 4, r = lane & 15;

    const float* qsrc = q + (((size_t)b * LN + ks * 512 + (lane >> 2)) * NH + h) * NE
                          + w * 16 + (lane & 3) * 4;
    const unsigned short* esrc = egf + (size_t)(ks * 16) * 4096 + w * 1024 + lane * 8;

#define STAGE_Q(T) { \
    __builtin_amdgcn_global_load_lds((gv_t*)(qsrc + (size_t)(T) * 32 * NC), \
        (lv_t*)(&qlds[(T) & 3][w][0][0]), 16, 0, 0); \
    __builtin_amdgcn_global_load_lds((gv_t*)(qsrc + ((size_t)(T) * 32 + 16) * NC), \
        (lv_t*)(&qlds[(T) & 3][w][16][0]), 16, 0, 0); }

#define STAGE_E(T) { \
    __builtin_amdgcn_global_load_lds((gv_t*)(esrc + (size_t)(T) * 4096), \
        (lv_t*)(&eglds[(T) & 3][w * 1024]), 16, 0, 0); \
    __builtin_amdgcn_global_load_lds((gv_t*)(esrc + (size_t)(T) * 4096 + 512), \
        (lv_t*)(&eglds[(T) & 3][w * 1024 + 512]), 16, 0, 0); }

    f32x4 acc[8];
    #pragma unroll
    for (int mt = 0; mt < 8; ++mt) acc[mt] = (f32x4)(0.0f);

    STAGE_Q(0) STAGE_E(0) STAGE_E(1) STAGE_Q(1) STAGE_Q(2)

    #pragma unroll
    for (int t = 0; t < 16; ++t) {
        if (t + 2 < 16) STAGE_E(t + 2)
        if (t <= 13)      asm volatile("s_waitcnt vmcnt(8)" ::: "memory");
        else if (t == 14) asm volatile("s_waitcnt vmcnt(4)" ::: "memory");
        else              asm volatile("s_waitcnt vmcnt(0)" ::: "memory");
        __builtin_amdgcn_s_barrier();
        asm volatile("" ::: "memory");
        if (t + 3 < 16) STAGE_Q(t + 3)

        s16x8 af[8];
        #pragma unroll
        for (int mt = 0; mt < 8; ++mt)
            af[mt] = *reinterpret_cast<const s16x8*>(&eglds[t & 3][mt * 512 + lane * 8]);
        s16x8 bfr;
        #pragma unroll
        for (int j = 0; j < 8; ++j)
            bfr[j] = (short)bf16bits(qlds[t & 3][w][g * 8 + j][r]);

        #pragma unroll
        for (int mt = 0; mt < 8; ++mt)
            acc[mt] = __builtin_amdgcn_mfma_f32_16x16x32_bf16(af[mt], bfr, acc[mt], 0, 0, 0);
    }
#undef STAGE_Q
#undef STAGE_E

    const int i = w * 16 + r;
    float* xpb = xp + ((size_t)ks * 64 + b * 8 + h) * (64 * 128) + (size_t)i * 128 + g * 4;
    #pragma unroll
    for (int mt = 0; mt < 8; ++mt)
        *reinterpret_cast<f32x4*>(xpb + mt * 16) = acc[mt];
}

// ---------------------------------------------------------------------------
// DIAGNOSTICS: fs1-v6 clones, rep=2, writing to xp2 scratch. Each isolates one
// consume-side component; each lands >40us -> visible in the rocprof top-5.
// ---------------------------------------------------------------------------
#define DIAG_BODY(BFR_CODE, AF_CODE, MFMA_CODE)                                   \
    __shared__ float qlds[4][4][32][16];                                          \
    __shared__ unsigned short eglds[4][4096];                                     \
    const int ks = blockIdx.x, h = blockIdx.y, b = blockIdx.z;                    \
    const int tid = threadIdx.x;                                                  \
    const int w = tid >> 6, lane = tid & 63;                                      \
    const int g = lane >> 4, r = lane & 15;                                       \
    const float* qsrc = q + (((size_t)b * LN + ks * 512 + (lane >> 2)) * NH + h) * NE \
                          + w * 16 + (lane & 3) * 4;                              \
    const unsigned short* esrc = egf + (size_t)(ks * 16) * 4096 + w * 1024 + lane * 8; \
    f32x4 acc[8];                                                                 \
    _Pragma("unroll")                                                             \
    for (int mt = 0; mt < 8; ++mt) acc[mt] = (f32x4)(0.0f);                       \
    for (int rep = 0; rep < 2; ++rep) {                                           \
        STAGE_Q(0) STAGE_E(0) STAGE_E(1) STAGE_Q(1) STAGE_Q(2)                    \
        _Pragma("unroll")                                                         \
        for (int t = 0; t < 16; ++t) {                                            \
            if (t + 2 < 16) STAGE_E(t + 2)                                        \
            if (t <= 13)      asm volatile("s_waitcnt vmcnt(8)" ::: "memory");    \
            else if (t == 14) asm volatile("s_waitcnt vmcnt(4)" ::: "memory");    \
            else              asm volatile("s_waitcnt vmcnt(0)" ::: "memory");    \
            __builtin_amdgcn_s_barrier();                                         \
            asm volatile("" ::: "memory");                                        \
            if (t + 3 < 16) STAGE_Q(t + 3)                                        \
            AF_CODE                                                               \
            BFR_CODE                                                              \
            MFMA_CODE                                                             \
        }                                                                         \
        asm volatile("s_waitcnt vmcnt(0)" ::: "memory");                          \
        __builtin_amdgcn_s_barrier();                                             \
    }                                                                             \
    const int i = w * 16 + r;                                                     \
    float* xpb = xp2 + ((size_t)ks * 64 + b * 8 + h) * (64 * 128) + (size_t)i * 128 + g * 4; \
    _Pragma("unroll")                                                             \
    for (int mt = 0; mt < 8; ++mt)                                                \
        *reinterpret_cast<f32x4*>(xpb + mt * 16) = acc[mt];

#define STAGE_Q(T) { \
    __builtin_amdgcn_global_load_lds((gv_t*)(qsrc + (size_t)(T) * 32 * NC), \
        (lv_t*)(&qlds[(T) & 3][w][0][0]), 16, 0, 0); \
    __builtin_amdgcn_global_load_lds((gv_t*)(qsrc + ((size_t)(T) * 32 + 16) * NC), \
        (lv_t*)(&qlds[(T) & 3][w][16][0]), 16, 0, 0); }
#define STAGE_E(T) { \
    __builtin_amdgcn_global_load_lds((gv_t*)(esrc + (size_t)(T) * 4096), \
        (lv_t*)(&eglds[(T) & 3][w * 1024]), 16, 0, 0); \
    __builtin_amdgcn_global_load_lds((gv_t*)(esrc + (size_t)(T) * 4096 + 512), \
        (lv_t*)(&eglds[(T) & 3][w * 1024 + 512]), 16, 0, 0); }

#define AF_FULL \
    s16x8 af[8]; \
    _Pragma("unroll") \
    for (int mt = 0; mt < 8; ++mt) \
        af[mt] = *reinterpret_cast<const s16x8*>(&eglds[t & 3][mt * 512 + lane * 8]);
#define AF_ONE \
    s16x8 af0 = *reinterpret_cast<const s16x8*>(&eglds[t & 3][lane * 8]);
#define BFR_FULL \
    s16x8 bfr; \
    _Pragma("unroll") \
    for (int j = 0; j < 8; ++j) bfr[j] = (short)bf16bits(qlds[t & 3][w][g * 8 + j][r]);
#define BFR_SPLAT \
    const short bs_ = (short)bf16bits(qlds[t & 3][w][g][r]); \
    s16x8 bfr; \
    _Pragma("unroll") \
    for (int j = 0; j < 8; ++j) bfr[j] = bs_;
#define MFMA_A8 \
    _Pragma("unroll") \
    for (int mt = 0; mt < 8; ++mt) \
        acc[mt] = __builtin_amdgcn_mfma_f32_16x16x32_bf16(af[mt], bfr, acc[mt], 0, 0, 0);
#define MFMA_A1 \
    _Pragma("unroll") \
    for (int mt = 0; mt < 8; ++mt) \
        acc[mt] = __builtin_amdgcn_mfma_f32_16x16x32_bf16(af0, bfr, acc[mt], 0, 0, 0);

// D1: full consume (exact fs1 cost x2)
__global__ __launch_bounds__(256, 2) void k_d1full(const float* __restrict__ q,
                                                   const unsigned short* __restrict__ egf,
                                                   float* __restrict__ xp2) {
    DIAG_BODY(BFR_FULL, AF_FULL, MFMA_A8)
}
// D2: bfr ablated (1 LDS read + 1 cvt, splat)
__global__ __launch_bounds__(256, 2) void k_d2nob(const float* __restrict__ q,
                                                  const unsigned short* __restrict__ egf,
                                                  float* __restrict__ xp2) {
    DIAG_BODY(BFR_SPLAT, AF_FULL, MFMA_A8)
}
// D3: af ablated (1 b128 reused x8)
__global__ __launch_bounds__(256, 2) void k_d3noa(const float* __restrict__ q,
                                                  const unsigned short* __restrict__ egf,
                                                  float* __restrict__ xp2) {
    DIAG_BODY(BFR_FULL, AF_ONE, MFMA_A1)
}
#undef STAGE_Q
#undef STAGE_E

// Sum the 8 K-split partials (float4-vectorized; same per-element order).
__global__ __launch_bounds__(256) void k_presum(const float* __restrict__ xp,
                                                float* __restrict__ xs) {
    int e4 = blockIdx.x * 256 + threadIdx.x;     // 0..131071 float4s
    const f32x4* xp4 = reinterpret_cast<const f32x4*>(xp);
    f32x4 s = (f32x4)(0.0f);
    #pragma unroll
    for (int ks = 0; ks < 8; ++ks) s += xp4[(size_t)ks * 131072 + e4];
    reinterpret_cast<f32x4*>(xs)[e4] = s;
}

// Stage 2 (v3, proven): channel mix, gf written directly.
__global__ __launch_bounds__(256) void k_s2(const float* __restrict__ w1,
                                            const float* __restrict__ w2,
                                            const float* __restrict__ xs,
                                            unsigned short* __restrict__ gf) {
    __shared__ float2 sxs[2][64][64];    // [bsub][i][m] = 64 KB
    const int sid = blockIdx.x;
    const int x   = sid & 7;
    const int idx = sid >> 3;
    const int r   = x * 8 + (idx & 7);   // (og,h) index
    const int og  = r >> 3, h = r & 7;
    const int bb  = idx >> 3;            // 0..3
    const int tt  = threadIdx.x;

    {
        float4* dst = reinterpret_cast<float4*>(&sxs[0][0][0]);
        #pragma unroll
        for (int bs = 0; bs < 2; ++bs) {
            const float4* s4 = reinterpret_cast<const float4*>(
                xs + ((size_t)((bb * 2 + bs) * 8 + h)) * 8192);
            #pragma unroll
            for (int k = 0; k < 8; ++k)
                dst[bs * 2048 + k * 256 + tt] = s4[k * 256 + tt];
        }
    }
    __syncthreads();

    const int m    = tt & 63;
    const int osub = tt >> 6;            // 0..3
    const int o0   = og * 8 + osub * 2;  // 2 o per thread

    float re[2][2], im[2][2];            // [oo][bs]
    #pragma unroll
    for (int oo = 0; oo < 2; ++oo)
        #pragma unroll
        for (int bs = 0; bs < 2; ++bs) { re[oo][bs] = 0.f; im[oo][bs] = 0.f; }

    const float* w1p = w1 + (size_t)h * (NE * NE * NM) + (size_t)o0 * NM + m;
    const float* w2p = w2 + (size_t)h * (NE * NE * NM) + (size_t)o0 * NM + m;

    #pragma unroll 2
    for (int i = 0; i < NE; ++i) {
        float wr0 = w1p[(size_t)i * (NE * NM)];
        float wi0 = w2p[(size_t)i * (NE * NM)];
        float wr1 = w1p[(size_t)i * (NE * NM) + NM];
        float wi1 = w2p[(size_t)i * (NE * NM) + NM];
        #pragma unroll
        for (int bs = 0; bs < 2; ++bs) {
            float2 xv = sxs[bs][i][m];
            re[0][bs] = fmaf(xv.x, wr0, fmaf(-xv.y, wi0, re[0][bs]));
            im[0][bs] = fmaf(xv.x, wi0, fmaf( xv.y, wr0, im[0][bs]));
            re[1][bs] = fmaf(xv.x, wr1, fmaf(-xv.y, wi1, re[1][bs]));
            im[1][bs] = fmaf(xv.x, wi1, fmaf( xv.y, wr1, im[1][bs]));
        }
    }

    const float sca = (m == 0 ? 1.0f : 2.0f) / (float)LN;  // (2-delta_m0)/L fold
    const int kk  = m >> 4;
    const int khi = ((m & 15) >> 2) * 16;
    const int jj  = (m & 3) << 1;
    #pragma unroll
    for (int oo = 0; oo < 2; ++oo) {
        const int c = h * 64 + o0 + oo;
        #pragma unroll
        for (int bs = 0; bs < 2; ++bs) {
            const int b = bb * 2 + bs;
            size_t slot = (((size_t)b * 4 + kk) * 32 + (c >> 4)) * 64 + khi + (c & 15);
            unsigned int pk = (unsigned)bf16bits(re[oo][bs] * sca) |
                              ((unsigned)bf16bits(-im[oo][bs] * sca) << 16);
            *reinterpret_cast<unsigned int*>(gf + slot * 8 + jj) = pk;
        }
    }
}

// Stage 3 MFMA (proven, near write-floor).
__global__ __launch_bounds__(256, 2) void k_s3(const unsigned short* __restrict__ gf,
                                               const unsigned short* __restrict__ tfp,
                                               float* __restrict__ out) {
    const int lb = blockIdx.x;   // l base = lb*64
    const int cb = blockIdx.y;   // c base = cb*128
    const int b  = blockIdx.z;
    const int tid = threadIdx.x;
    const int w = tid >> 6, lane = tid & 63;

    const unsigned short* ga = gf + ((((size_t)b * 4) * 32 + cb * 8 + w * 2) * 64 + lane) * 8;
    const unsigned short* tb = tfp + (((size_t)lb * 4) * 64 + lane) * 8;

    f32x4 acc[2][4] = {};
    s16x8 af[3][2], bf[3][4];

#define S3_LOAD(T, SLOT)                                                          \
    {                                                                             \
        const unsigned short* gp_ = ga + (size_t)(T) * (32 * 64 * 8);             \
        const unsigned short* tp_ = tb + (size_t)(T) * (256 * 64 * 8);            \
        af[SLOT][0] = *reinterpret_cast<const s16x8*>(gp_);                       \
        af[SLOT][1] = *reinterpret_cast<const s16x8*>(gp_ + 64 * 8);              \
        bf[SLOT][0] = *reinterpret_cast<const s16x8*>(tp_);                       \
        bf[SLOT][1] = *reinterpret_cast<const s16x8*>(tp_ + 64 * 8);              \
        bf[SLOT][2] = *reinterpret_cast<const s16x8*>(tp_ + 2 * 64 * 8);          \
        bf[SLOT][3] = *reinterpret_cast<const s16x8*>(tp_ + 3 * 64 * 8);          \
    }

    S3_LOAD(0, 0)
    S3_LOAD(1, 1)

    #pragma unroll
    for (int t = 0; t < 4; ++t) {
        const int slot = t % 3;
        if (t + 2 < 4) { const int ns = (t + 2) % 3; S3_LOAD(t + 2, ns) }
        #pragma unroll
        for (int mi = 0; mi < 2; ++mi)
            #pragma unroll
            for (int ni = 0; ni < 4; ++ni)
                acc[mi][ni] = __builtin_amdgcn_mfma_f32_16x16x32_bf16(
                    af[slot][mi], bf[slot][ni], acc[mi][ni], 0, 0, 0);
    }
#undef S3_LOAD

    const int c0 = cb * 128 + w * 32 + (lane >> 4) * 4;
    const int l0 = lb * 64 + (lane & 15);
    #pragma unroll
    for (int mi = 0; mi < 2; ++mi)
        #pragma unroll
        for (int ni = 0; ni < 4; ++ni) {
            float* op = out + ((size_t)b * LN + l0 + ni * 16) * NC + c0 + mi * 16;
            *reinterpret_cast<f32x4*>(op) = acc[mi][ni];
        }
}

extern "C" void kernel_launch(void* const* d_in, const int* in_sizes, int n_in,
                              void* d_out, int out_size, void* d_ws, size_t ws_size,
                              hipStream_t stream) {
    const float* q  = (const float*)d_in[0];
    // d_in[1] (k) and d_in[2] (v) are unused by the reference
    const float* w1 = (const float*)d_in[3];
    const float* w2 = (const float*)d_in[4];
    float* out = (float*)d_out;
    float* ws  = (float*)d_ws;

    unsigned short* egf = (unsigned short*)(ws + WS_EGF);
    unsigned short* tfp = (unsigned short*)(ws + WS_TF);
    unsigned short* gf  = (unsigned short*)(ws + WS_GF);
    float*          xp  = ws + WS_XP;
    float*          xs  = ws + WS_XS;
    float*          xp2 = ws + WS_XP2;

    k_tables<<<512, 256, 0, stream>>>(egf, tfp);
    k_fs1<<<dim3(8, NH, NB), 256, 0, stream>>>(q, egf, xp);
    k_presum<<<512, 256, 0, stream>>>(xp, xs);
    k_s2<<<256, 256, 0, stream>>>(w1, w2, xs, gf);
    k_s3<<<dim3(64, 4, NB), 256, 0, stream>>>(gf, tfp, out);
    // diagnostics (scratch writes, rep=2 each -> individually visible in top-5)
    k_d1full<<<dim3(8, NH, NB), 256, 0, stream>>>(q, egf, xp2);
    k_d2nob<<<dim3(8, NH, NB), 256, 0, stream>>>(q, egf, xp2);
    k_d3noa<<<dim3(8, NH, NB), 256, 0, stream>>>(q, egf, xp2);
}

// Round 14
// 56.994 us; speedup vs baseline: 2.4240x; 2.4240x over previous
//
#include <hip/hip_runtime.h>
#include <hip/hip_bf16.h>
#include <math.h>

// Problem constants
#define NB 8
#define LN 4096       // sequence length L
#define NH 8
#define NE 64
#define NC 512        // NH*NE channels
#define NM 64         // modes kept
#define LMASK 4095

typedef short s16x8 __attribute__((ext_vector_type(8)));
typedef float f32x4 __attribute__((ext_vector_type(4)));
typedef const __attribute__((address_space(1))) void gv_t;
typedef __attribute__((address_space(3))) void lv_t;

// ws layout (in floats):
//  egf : bf16[128kc][8mt][64][8]        @ 0        (1 MB)  fwd twiddle A-fragments
//  tf  : bf16[4kk][256lt][64][8]        @ 262144   (1 MB)  inv twiddle B-fragments
//  gf  : bf16[8b][4kk][32ct][64][8]     @ 524288   (1 MB)  mixed-spectrum A-fragments
//  xp  : f32[8ks][8b][8h][64i][128m±]   @ 786432   (16 MB) partial fwd GEMM outputs
//  xs  : f32[8b][8h][64i][128m±]        @ 4980736  (2 MB)  ks-summed spectrum
#define WS_EGF 0
#define WS_TF  262144
#define WS_GF  524288
#define WS_XP  786432
#define WS_XS  4980736

static __device__ __forceinline__ unsigned short bf16bits(float f) {
    __hip_bfloat16 b = __float2bfloat16(f);
    return *reinterpret_cast<unsigned short*>(&b);
}

// Both twiddle tables in one launch. Blocks 0..255: egf (fwd A-frags);
// blocks 256..511: tf (inv B-frags).
__global__ __launch_bounds__(256) void k_tables(unsigned short* __restrict__ egf,
                                                unsigned short* __restrict__ tfp) {
    const int bid = blockIdx.x;
    const int s = (bid & 255) * 256 + threadIdx.x;   // 0..65535
    const int lane = s & 63;
    unsigned short v[8];
    if (bid < 256) {
        // E[2m][l]=cos, E[2m+1][l]=-sin ; slot s=(kc<<9)|(mt<<6)|lane
        int mt = (s >> 6) & 7, kc = s >> 9;
        int r = lane & 15, kg = lane >> 4;
        int mpm = mt * 16 + r;
        int m = mpm >> 1, isim = mpm & 1;
        #pragma unroll
        for (int j = 0; j < 8; ++j) {
            int l = kc * 32 + kg * 8 + j;
            int tw = (m * l) & LMASK;
            float ang = (6.283185307179586f / 4096.0f) * (float)tw;
            v[j] = bf16bits(isim ? -sinf(ang) : cosf(ang));
        }
    } else {
        // T[l][2m]=cos, T[l][2m+1]=sin ; slot s=(kk<<14)|(lt<<6)|lane
        int lt = (s >> 6) & 255, kk = s >> 14;
        int l = lt * 16 + (lane & 15);
        int khi = (lane >> 4) * 8;
        #pragma unroll
        for (int j = 0; j < 8; ++j) {
            int mp = kk * 32 + khi + j;
            int m = mp >> 1;
            int tw = (m * l) & LMASK;
            float ang = (6.283185307179586f / 4096.0f) * (float)tw;
            v[j] = bf16bits((mp & 1) ? sinf(ang) : cosf(ang));
        }
    }
    uint4 pk;
    pk.x = (unsigned)v[0] | ((unsigned)v[1] << 16);
    pk.y = (unsigned)v[2] | ((unsigned)v[3] << 16);
    pk.z = (unsigned)v[4] | ((unsigned)v[5] << 16);
    pk.w = (unsigned)v[6] | ((unsigned)v[7] << 16);
    unsigned short* dst = (bid < 256) ? egf : tfp;
    *reinterpret_cast<uint4*>(dst + (size_t)s * 8) = pk;
}

// Fused stage 1 (v6, round-10 verbatim — measured ~12-19 us, near its ~11 us
// floor per the round-13 ablation; LEFT UNTOUCHED).
__global__ __launch_bounds__(256, 2) void k_fs1(const float* __restrict__ q,
                                                const unsigned short* __restrict__ egf,
                                                float* __restrict__ xp) {
    __shared__ float qlds[4][4][32][16];        // 32 KB: [slot][wave][l][i]
    __shared__ unsigned short eglds[4][4096];   // 32 KB: [slot][frag bytes of one kc]
    const int ks = blockIdx.x, h = blockIdx.y, b = blockIdx.z;
    const int tid = threadIdx.x;
    const int w = tid >> 6, lane = tid & 63;
    const int g = lane >> 4, r = lane & 15;

    const float* qsrc = q + (((size_t)b * LN + ks * 512 + (lane >> 2)) * NH + h) * NE
                          + w * 16 + (lane & 3) * 4;
    const unsigned short* esrc = egf + (size_t)(ks * 16) * 4096 + w * 1024 + lane * 8;

#define STAGE_Q(T) { \
    __builtin_amdgcn_global_load_lds((gv_t*)(qsrc + (size_t)(T) * 32 * NC), \
        (lv_t*)(&qlds[(T) & 3][w][0][0]), 16, 0, 0); \
    __builtin_amdgcn_global_load_lds((gv_t*)(qsrc + ((size_t)(T) * 32 + 16) * NC), \
        (lv_t*)(&qlds[(T) & 3][w][16][0]), 16, 0, 0); }

#define STAGE_E(T) { \
    __builtin_amdgcn_global_load_lds((gv_t*)(esrc + (size_t)(T) * 4096), \
        (lv_t*)(&eglds[(T) & 3][w * 1024]), 16, 0, 0); \
    __builtin_amdgcn_global_load_lds((gv_t*)(esrc + (size_t)(T) * 4096 + 512), \
        (lv_t*)(&eglds[(T) & 3][w * 1024 + 512]), 16, 0, 0); }

    f32x4 acc[8];
    #pragma unroll
    for (int mt = 0; mt < 8; ++mt) acc[mt] = (f32x4)(0.0f);

    STAGE_Q(0) STAGE_E(0) STAGE_E(1) STAGE_Q(1) STAGE_Q(2)

    #pragma unroll
    for (int t = 0; t < 16; ++t) {
        if (t + 2 < 16) STAGE_E(t + 2)
        if (t <= 13)      asm volatile("s_waitcnt vmcnt(8)" ::: "memory");
        else if (t == 14) asm volatile("s_waitcnt vmcnt(4)" ::: "memory");
        else              asm volatile("s_waitcnt vmcnt(0)" ::: "memory");
        __builtin_amdgcn_s_barrier();
        asm volatile("" ::: "memory");
        if (t + 3 < 16) STAGE_Q(t + 3)

        s16x8 af[8];
        #pragma unroll
        for (int mt = 0; mt < 8; ++mt)
            af[mt] = *reinterpret_cast<const s16x8*>(&eglds[t & 3][mt * 512 + lane * 8]);
        s16x8 bfr;
        #pragma unroll
        for (int j = 0; j < 8; ++j)
            bfr[j] = (short)bf16bits(qlds[t & 3][w][g * 8 + j][r]);

        #pragma unroll
        for (int mt = 0; mt < 8; ++mt)
            acc[mt] = __builtin_amdgcn_mfma_f32_16x16x32_bf16(af[mt], bfr, acc[mt], 0, 0, 0);
    }
#undef STAGE_Q
#undef STAGE_E

    const int i = w * 16 + r;
    float* xpb = xp + ((size_t)ks * 64 + b * 8 + h) * (64 * 128) + (size_t)i * 128 + g * 4;
    #pragma unroll
    for (int mt = 0; mt < 8; ++mt)
        *reinterpret_cast<f32x4*>(xpb + mt * 16) = acc[mt];
}

// Sum the 8 K-split partials. Non-temporal loads: xp is read exactly once,
// so don't evict L2/L3 lines that s2/s3 will want. Same fp order -> bit-exact.
__global__ __launch_bounds__(256) void k_presum(const float* __restrict__ xp,
                                                float* __restrict__ xs) {
    int e4 = blockIdx.x * 256 + threadIdx.x;     // 0..131071 float4s
    const f32x4* xp4 = reinterpret_cast<const f32x4*>(xp);
    f32x4 s = (f32x4)(0.0f);
    #pragma unroll
    for (int ks = 0; ks < 8; ++ks)
        s += __builtin_nontemporal_load(&xp4[(size_t)ks * 131072 + e4]);
    reinterpret_cast<f32x4*>(xs)[e4] = s;
}

// Stage 2 (v3 + unroll-8 on the i-loop): the w-loads stride 16 KB; unroll 2
// left only 8 loads in flight (~32 serial latency batches at 1 block/CU).
// unroll 8 -> 32 outstanding loads. Per-accumulator fmaf order unchanged ->
// bit-exact. Grid 256 blocks (XCD-swizzled), w1/w2 read exactly once.
__global__ __launch_bounds__(256) void k_s2(const float* __restrict__ w1,
                                            const float* __restrict__ w2,
                                            const float* __restrict__ xs,
                                            unsigned short* __restrict__ gf) {
    __shared__ float2 sxs[2][64][64];    // [bsub][i][m] = 64 KB
    const int sid = blockIdx.x;
    const int x   = sid & 7;
    const int idx = sid >> 3;
    const int r   = x * 8 + (idx & 7);   // (og,h) index
    const int og  = r >> 3, h = r & 7;
    const int bb  = idx >> 3;            // 0..3
    const int tt  = threadIdx.x;

    {
        float4* dst = reinterpret_cast<float4*>(&sxs[0][0][0]);
        #pragma unroll
        for (int bs = 0; bs < 2; ++bs) {
            const float4* s4 = reinterpret_cast<const float4*>(
                xs + ((size_t)((bb * 2 + bs) * 8 + h)) * 8192);
            #pragma unroll
            for (int k = 0; k < 8; ++k)
                dst[bs * 2048 + k * 256 + tt] = s4[k * 256 + tt];
        }
    }
    __syncthreads();

    const int m    = tt & 63;
    const int osub = tt >> 6;            // 0..3
    const int o0   = og * 8 + osub * 2;  // 2 o per thread

    float re[2][2], im[2][2];            // [oo][bs]
    #pragma unroll
    for (int oo = 0; oo < 2; ++oo)
        #pragma unroll
        for (int bs = 0; bs < 2; ++bs) { re[oo][bs] = 0.f; im[oo][bs] = 0.f; }

    const float* w1p = w1 + (size_t)h * (NE * NE * NM) + (size_t)o0 * NM + m;
    const float* w2p = w2 + (size_t)h * (NE * NE * NM) + (size_t)o0 * NM + m;

    #pragma unroll 8
    for (int i = 0; i < NE; ++i) {
        float wr0 = w1p[(size_t)i * (NE * NM)];
        float wi0 = w2p[(size_t)i * (NE * NM)];
        float wr1 = w1p[(size_t)i * (NE * NM) + NM];
        float wi1 = w2p[(size_t)i * (NE * NM) + NM];
        #pragma unroll
        for (int bs = 0; bs < 2; ++bs) {
            float2 xv = sxs[bs][i][m];
            re[0][bs] = fmaf(xv.x, wr0, fmaf(-xv.y, wi0, re[0][bs]));
            im[0][bs] = fmaf(xv.x, wi0, fmaf( xv.y, wr0, im[0][bs]));
            re[1][bs] = fmaf(xv.x, wr1, fmaf(-xv.y, wi1, re[1][bs]));
            im[1][bs] = fmaf(xv.x, wi1, fmaf( xv.y, wr1, im[1][bs]));
        }
    }

    const float sca = (m == 0 ? 1.0f : 2.0f) / (float)LN;  // (2-delta_m0)/L fold
    // G[2m][c]=s*re, G[2m+1][c]=-s*im into A-fragment layout:
    // slot = ((b*4 + (m>>4))*32 + (c>>4))*64 + ((m&15)>>2)*16 + (c&15), elems ((m&3)<<1)+{0,1}
    const int kk  = m >> 4;
    const int khi = ((m & 15) >> 2) * 16;
    const int jj  = (m & 3) << 1;
    #pragma unroll
    for (int oo = 0; oo < 2; ++oo) {
        const int c = h * 64 + o0 + oo;
        #pragma unroll
        for (int bs = 0; bs < 2; ++bs) {
            const int b = bb * 2 + bs;
            size_t slot = (((size_t)b * 4 + kk) * 32 + (c >> 4)) * 64 + khi + (c & 15);
            unsigned int pk = (unsigned)bf16bits(re[oo][bs] * sca) |
                              ((unsigned)bf16bits(-im[oo][bs] * sca) << 16);
            *reinterpret_cast<unsigned int*>(gf + slot * 8 + jj) = pk;
        }
    }
}

// Stage 3 MFMA: per b: out[l][c] = sum_mp T[l][mp] * G[mp][c].
// grid (64 lb, 4 cb, 8 b), block 256 = 4 waves. Non-temporal out stores:
// 64 MB streaming with zero reuse — keep L2 for gf/tf operand streams.
__global__ __launch_bounds__(256, 2) void k_s3(const unsigned short* __restrict__ gf,
                                               const unsigned short* __restrict__ tfp,
                                               float* __restrict__ out) {
    const int lb = blockIdx.x;   // l base = lb*64
    const int cb = blockIdx.y;   // c base = cb*128
    const int b  = blockIdx.z;
    const int tid = threadIdx.x;
    const int w = tid >> 6, lane = tid & 63;

    const unsigned short* ga = gf + ((((size_t)b * 4) * 32 + cb * 8 + w * 2) * 64 + lane) * 8;
    const unsigned short* tb = tfp + (((size_t)lb * 4) * 64 + lane) * 8;

    f32x4 acc[2][4] = {};
    s16x8 af[3][2], bf[3][4];

#define S3_LOAD(T, SLOT)                                                          \
    {                                                                             \
        const unsigned short* gp_ = ga + (size_t)(T) * (32 * 64 * 8);             \
        const unsigned short* tp_ = tb + (size_t)(T) * (256 * 64 * 8);            \
        af[SLOT][0] = *reinterpret_cast<const s16x8*>(gp_);                       \
        af[SLOT][1] = *reinterpret_cast<const s16x8*>(gp_ + 64 * 8);              \
        bf[SLOT][0] = *reinterpret_cast<const s16x8*>(tp_);                       \
        bf[SLOT][1] = *reinterpret_cast<const s16x8*>(tp_ + 64 * 8);              \
        bf[SLOT][2] = *reinterpret_cast<const s16x8*>(tp_ + 2 * 64 * 8);          \
        bf[SLOT][3] = *reinterpret_cast<const s16x8*>(tp_ + 3 * 64 * 8);          \
    }

    S3_LOAD(0, 0)
    S3_LOAD(1, 1)

    #pragma unroll
    for (int t = 0; t < 4; ++t) {
        const int slot = t % 3;
        if (t + 2 < 4) { const int ns = (t + 2) % 3; S3_LOAD(t + 2, ns) }
        #pragma unroll
        for (int mi = 0; mi < 2; ++mi)
            #pragma unroll
            for (int ni = 0; ni < 4; ++ni)
                acc[mi][ni] = __builtin_amdgcn_mfma_f32_16x16x32_bf16(
                    af[slot][mi], bf[slot][ni], acc[mi][ni], 0, 0, 0);
    }
#undef S3_LOAD

    // D[row=c_local][col=l_local]; f32x4 regs span 4 consecutive c.
    const int c0 = cb * 128 + w * 32 + (lane >> 4) * 4;
    const int l0 = lb * 64 + (lane & 15);
    #pragma unroll
    for (int mi = 0; mi < 2; ++mi)
        #pragma unroll
        for (int ni = 0; ni < 4; ++ni) {
            float* op = out + ((size_t)b * LN + l0 + ni * 16) * NC + c0 + mi * 16;
            __builtin_nontemporal_store(acc[mi][ni], reinterpret_cast<f32x4*>(op));
        }
}

extern "C" void kernel_launch(void* const* d_in, const int* in_sizes, int n_in,
                              void* d_out, int out_size, void* d_ws, size_t ws_size,
                              hipStream_t stream) {
    const float* q  = (const float*)d_in[0];
    // d_in[1] (k) and d_in[2] (v) are unused by the reference
    const float* w1 = (const float*)d_in[3];
    const float* w2 = (const float*)d_in[4];
    float* out = (float*)d_out;
    float* ws  = (float*)d_ws;

    unsigned short* egf = (unsigned short*)(ws + WS_EGF);
    unsigned short* tfp = (unsigned short*)(ws + WS_TF);
    unsigned short* gf  = (unsigned short*)(ws + WS_GF);
    float*          xp  = ws + WS_XP;
    float*          xs  = ws + WS_XS;

    k_tables<<<512, 256, 0, stream>>>(egf, tfp);
    k_fs1<<<dim3(8, NH, NB), 256, 0, stream>>>(q, egf, xp);
    k_presum<<<512, 256, 0, stream>>>(xp, xs);
    k_s2<<<256, 256, 0, stream>>>(w1, w2, xs, gf);
    k_s3<<<dim3(64, 4, NB), 256, 0, stream>>>(gf, tfp, out);
}

// Round 15
// 53.903 us; speedup vs baseline: 2.5630x; 1.0573x over previous
//
#include <hip/hip_runtime.h>
#include <hip/hip_bf16.h>
#include <math.h>

// Problem constants
#define NB 8
#define LN 4096       // sequence length L
#define NH 8
#define NE 64
#define NC 512        // NH*NE channels
#define NM 64         // modes kept
#define LMASK 4095

typedef short s16x8 __attribute__((ext_vector_type(8)));
typedef float f32x4 __attribute__((ext_vector_type(4)));
typedef const __attribute__((address_space(1))) void gv_t;
typedef __attribute__((address_space(3))) void lv_t;

// ws layout (in floats):
//  tf  : bf16[4kk][256lt][64][8]        @ 262144   (1 MB)  inv twiddle B-fragments
//  gf  : bf16[8b][4kk][32ct][64][8]     @ 524288   (1 MB)  mixed-spectrum A-fragments
//  xp  : f32[8ks][8b][8h][64i][128m±]   @ 786432   (16 MB) partial fwd GEMM outputs
//  xs  : f32[8b][8h][64i][128m±]        @ 4980736  (2 MB)  ks-summed spectrum
#define WS_TF  262144
#define WS_GF  524288
#define WS_XP  786432
#define WS_XS  4980736

static __device__ __forceinline__ unsigned short bf16bits(float f) {
    __hip_bfloat16 b = __float2bfloat16(f);
    return *reinterpret_cast<unsigned short*>(&b);
}

// Fused stage 1 (v8 = v6 pipeline, egf computed IN-KERNEL into a 2-slot LDS ring;
// k_tables launch eliminated). grid (8 ks, 8 h, 8 b), 256 thr = 4 waves, 2 blk/CU.
// Per tile t: thread computes its 16 twiddle bf16s (8 cos + 8 -sin, same angle set,
// fast __sinf/__cosf — bf16 quantization dominates the trig-precision delta),
// 2x ds_write_b128; then vmcnt(q-only: 4/2/0), lgkmcnt(0), raw barrier, consume.
// qlds 4-slot depth-3 DMA ring unchanged from v6.
__global__ __launch_bounds__(256, 2) void k_fs1(const float* __restrict__ q,
                                                float* __restrict__ xp) {
    __shared__ float qlds[4][4][32][16];        // 32 KB: [slot][wave][l][i]
    __shared__ unsigned short eglds[2][4096];   // 16 KB: [slot][one kc's fragments]
    const int ks = blockIdx.x, h = blockIdx.y, b = blockIdx.z;
    const int tid = threadIdx.x;
    const int w = tid >> 6, lane = tid & 63;
    const int g = lane >> 4, r = lane & 15;

    const float* qsrc = q + (((size_t)b * LN + ks * 512 + (lane >> 2)) * NH + h) * NE
                          + w * 16 + (lane & 3) * 4;

    // Twiddle-generation constants: thread tid covers eglds shorts [tid*16, tid*16+16):
    // idx = mt*512 + lane_c*8 + j with mt = tid>>5, lane_c in {2*tid, 2*tid+1} (&63).
    // Group e<8: mpm even -> cos ; group e>=8: mpm odd -> -sin ; same m, same angles.
    const int m_tw  = (tid >> 5) * 8 + (tid & 7);   // mode m (both groups)
    const int kg_tw = (tid >> 3) & 3;               // l-octet within the 32-l tile

#define STAGE_Q(T) { \
    __builtin_amdgcn_global_load_lds((gv_t*)(qsrc + (size_t)(T) * 32 * NC), \
        (lv_t*)(&qlds[(T) & 3][w][0][0]), 16, 0, 0); \
    __builtin_amdgcn_global_load_lds((gv_t*)(qsrc + ((size_t)(T) * 32 + 16) * NC), \
        (lv_t*)(&qlds[(T) & 3][w][16][0]), 16, 0, 0); }

    f32x4 acc[8];
    #pragma unroll
    for (int mt = 0; mt < 8; ++mt) acc[mt] = (f32x4)(0.0f);

    STAGE_Q(0) STAGE_Q(1) STAGE_Q(2)

    #pragma unroll
    for (int t = 0; t < 16; ++t) {
        // ---- generate egf tile t (kc = ks*16 + t) into eglds[t&1] ----
        {
            const int kc = ks * 16 + t;
            int tw = (m_tw * (kc * 32 + kg_tw * 8)) & LMASK;
            unsigned short vc[8], vs[8];
            #pragma unroll
            for (int j = 0; j < 8; ++j) {
                float ang = (6.283185307179586f / 4096.0f) * (float)tw;
                vc[j] = bf16bits(__cosf(ang));
                vs[j] = bf16bits(-__sinf(ang));
                tw = (tw + m_tw) & LMASK;
            }
            uint4 p0, p1;
            p0.x = (unsigned)vc[0] | ((unsigned)vc[1] << 16);
            p0.y = (unsigned)vc[2] | ((unsigned)vc[3] << 16);
            p0.z = (unsigned)vc[4] | ((unsigned)vc[5] << 16);
            p0.w = (unsigned)vc[6] | ((unsigned)vc[7] << 16);
            p1.x = (unsigned)vs[0] | ((unsigned)vs[1] << 16);
            p1.y = (unsigned)vs[2] | ((unsigned)vs[3] << 16);
            p1.z = (unsigned)vs[4] | ((unsigned)vs[5] << 16);
            p1.w = (unsigned)vs[6] | ((unsigned)vs[7] << 16);
            *reinterpret_cast<uint4*>(&eglds[t & 1][tid * 16])     = p0;
            *reinterpret_cast<uint4*>(&eglds[t & 1][tid * 16 + 8]) = p1;
        }
        // q-only vmcnt: keep {q(t+1), q(t+2)} = 4 ops in flight; drain the tail.
        if (t <= 13)      asm volatile("s_waitcnt vmcnt(4)" ::: "memory");
        else if (t == 14) asm volatile("s_waitcnt vmcnt(2)" ::: "memory");
        else              asm volatile("s_waitcnt vmcnt(0)" ::: "memory");
        asm volatile("s_waitcnt lgkmcnt(0)" ::: "memory");   // eglds writes visible
        __builtin_amdgcn_s_barrier();                         // raw: no vmcnt drain
        asm volatile("" ::: "memory");
        if (t + 3 < 16) STAGE_Q(t + 3)

        // A fragments from the in-LDS twiddle tile
        s16x8 af[8];
        #pragma unroll
        for (int mt = 0; mt < 8; ++mt)
            af[mt] = *reinterpret_cast<const s16x8*>(&eglds[t & 1][mt * 512 + lane * 8]);
        // B fragment: f32 gather from own wave's staged subtile, RNE cvt (unchanged)
        s16x8 bfr;
        #pragma unroll
        for (int j = 0; j < 8; ++j)
            bfr[j] = (short)bf16bits(qlds[t & 3][w][g * 8 + j][r]);

        #pragma unroll
        for (int mt = 0; mt < 8; ++mt)
            acc[mt] = __builtin_amdgcn_mfma_f32_16x16x32_bf16(af[mt], bfr, acc[mt], 0, 0, 0);
    }
#undef STAGE_Q

    // Epilogue: D row = m±-local = (lane>>4)*4 + reg, col = i-local = lane&15.
    const int i = w * 16 + r;
    float* xpb = xp + ((size_t)ks * 64 + b * 8 + h) * (64 * 128) + (size_t)i * 128 + g * 4;
    #pragma unroll
    for (int mt = 0; mt < 8; ++mt)
        *reinterpret_cast<f32x4*>(xpb + mt * 16) = acc[mt];
}

// presum (blocks 0..511) + tf generation (blocks 512..767, bit-identical to the
// old k_tables tf branch: precise sinf/cosf). One launch replaces two.
__global__ __launch_bounds__(256) void k_presum(const float* __restrict__ xp,
                                                float* __restrict__ xs,
                                                unsigned short* __restrict__ tfp) {
    const int bid = blockIdx.x;
    if (bid < 512) {
        int e4 = bid * 256 + threadIdx.x;     // 0..131071 float4s
        const f32x4* xp4 = reinterpret_cast<const f32x4*>(xp);
        f32x4 s = (f32x4)(0.0f);
        #pragma unroll
        for (int ks = 0; ks < 8; ++ks)
            s += __builtin_nontemporal_load(&xp4[(size_t)ks * 131072 + e4]);
        reinterpret_cast<f32x4*>(xs)[e4] = s;
        return;
    }
    // tf: T[l][2m]=cos, T[l][2m+1]=sin ; slot s=(kk<<14)|(lt<<6)|lane
    const int s = (bid - 512) * 256 + threadIdx.x;   // 0..65535
    const int lane = s & 63;
    const int lt = (s >> 6) & 255, kk = s >> 14;
    const int l = lt * 16 + (lane & 15);
    const int khi = (lane >> 4) * 8;
    unsigned short v[8];
    #pragma unroll
    for (int j = 0; j < 8; ++j) {
        int mp = kk * 32 + khi + j;
        int m = mp >> 1;
        int tw = (m * l) & LMASK;
        float ang = (6.283185307179586f / 4096.0f) * (float)tw;
        v[j] = bf16bits((mp & 1) ? sinf(ang) : cosf(ang));
    }
    uint4 pk;
    pk.x = (unsigned)v[0] | ((unsigned)v[1] << 16);
    pk.y = (unsigned)v[2] | ((unsigned)v[3] << 16);
    pk.z = (unsigned)v[4] | ((unsigned)v[5] << 16);
    pk.w = (unsigned)v[6] | ((unsigned)v[7] << 16);
    *reinterpret_cast<uint4*>(tfp + (size_t)s * 8) = pk;
}

// Stage 2 (round-14 proven: LDS-staged, unroll-8 w-stream, w1/w2 read once).
__global__ __launch_bounds__(256) void k_s2(const float* __restrict__ w1,
                                            const float* __restrict__ w2,
                                            const float* __restrict__ xs,
                                            unsigned short* __restrict__ gf) {
    __shared__ float2 sxs[2][64][64];    // [bsub][i][m] = 64 KB
    const int sid = blockIdx.x;
    const int x   = sid & 7;
    const int idx = sid >> 3;
    const int r   = x * 8 + (idx & 7);   // (og,h) index
    const int og  = r >> 3, h = r & 7;
    const int bb  = idx >> 3;            // 0..3
    const int tt  = threadIdx.x;

    {
        float4* dst = reinterpret_cast<float4*>(&sxs[0][0][0]);
        #pragma unroll
        for (int bs = 0; bs < 2; ++bs) {
            const float4* s4 = reinterpret_cast<const float4*>(
                xs + ((size_t)((bb * 2 + bs) * 8 + h)) * 8192);
            #pragma unroll
            for (int k = 0; k < 8; ++k)
                dst[bs * 2048 + k * 256 + tt] = s4[k * 256 + tt];
        }
    }
    __syncthreads();

    const int m    = tt & 63;
    const int osub = tt >> 6;            // 0..3
    const int o0   = og * 8 + osub * 2;  // 2 o per thread

    float re[2][2], im[2][2];            // [oo][bs]
    #pragma unroll
    for (int oo = 0; oo < 2; ++oo)
        #pragma unroll
        for (int bs = 0; bs < 2; ++bs) { re[oo][bs] = 0.f; im[oo][bs] = 0.f; }

    const float* w1p = w1 + (size_t)h * (NE * NE * NM) + (size_t)o0 * NM + m;
    const float* w2p = w2 + (size_t)h * (NE * NE * NM) + (size_t)o0 * NM + m;

    #pragma unroll 8
    for (int i = 0; i < NE; ++i) {
        float wr0 = w1p[(size_t)i * (NE * NM)];
        float wi0 = w2p[(size_t)i * (NE * NM)];
        float wr1 = w1p[(size_t)i * (NE * NM) + NM];
        float wi1 = w2p[(size_t)i * (NE * NM) + NM];
        #pragma unroll
        for (int bs = 0; bs < 2; ++bs) {
            float2 xv = sxs[bs][i][m];
            re[0][bs] = fmaf(xv.x, wr0, fmaf(-xv.y, wi0, re[0][bs]));
            im[0][bs] = fmaf(xv.x, wi0, fmaf( xv.y, wr0, im[0][bs]));
            re[1][bs] = fmaf(xv.x, wr1, fmaf(-xv.y, wi1, re[1][bs]));
            im[1][bs] = fmaf(xv.x, wi1, fmaf( xv.y, wr1, im[1][bs]));
        }
    }

    const float sca = (m == 0 ? 1.0f : 2.0f) / (float)LN;  // (2-delta_m0)/L fold
    // G[2m][c]=s*re, G[2m+1][c]=-s*im into A-fragment layout:
    // slot = ((b*4 + (m>>4))*32 + (c>>4))*64 + ((m&15)>>2)*16 + (c&15), elems ((m&3)<<1)+{0,1}
    const int kk  = m >> 4;
    const int khi = ((m & 15) >> 2) * 16;
    const int jj  = (m & 3) << 1;
    #pragma unroll
    for (int oo = 0; oo < 2; ++oo) {
        const int c = h * 64 + o0 + oo;
        #pragma unroll
        for (int bs = 0; bs < 2; ++bs) {
            const int b = bb * 2 + bs;
            size_t slot = (((size_t)b * 4 + kk) * 32 + (c >> 4)) * 64 + khi + (c & 15);
            unsigned int pk = (unsigned)bf16bits(re[oo][bs] * sca) |
                              ((unsigned)bf16bits(-im[oo][bs] * sca) << 16);
            *reinterpret_cast<unsigned int*>(gf + slot * 8 + jj) = pk;
        }
    }
}

// Stage 3 MFMA (round-14 proven, NT stores, near write-floor).
__global__ __launch_bounds__(256, 2) void k_s3(const unsigned short* __restrict__ gf,
                                               const unsigned short* __restrict__ tfp,
                                               float* __restrict__ out) {
    const int lb = blockIdx.x;   // l base = lb*64
    const int cb = blockIdx.y;   // c base = cb*128
    const int b  = blockIdx.z;
    const int tid = threadIdx.x;
    const int w = tid >> 6, lane = tid & 63;

    const unsigned short* ga = gf + ((((size_t)b * 4) * 32 + cb * 8 + w * 2) * 64 + lane) * 8;
    const unsigned short* tb = tfp + (((size_t)lb * 4) * 64 + lane) * 8;

    f32x4 acc[2][4] = {};
    s16x8 af[3][2], bf[3][4];

#define S3_LOAD(T, SLOT)                                                          \
    {                                                                             \
        const unsigned short* gp_ = ga + (size_t)(T) * (32 * 64 * 8);             \
        const unsigned short* tp_ = tb + (size_t)(T) * (256 * 64 * 8);            \
        af[SLOT][0] = *reinterpret_cast<const s16x8*>(gp_);                       \
        af[SLOT][1] = *reinterpret_cast<const s16x8*>(gp_ + 64 * 8);              \
        bf[SLOT][0] = *reinterpret_cast<const s16x8*>(tp_);                       \
        bf[SLOT][1] = *reinterpret_cast<const s16x8*>(tp_ + 64 * 8);              \
        bf[SLOT][2] = *reinterpret_cast<const s16x8*>(tp_ + 2 * 64 * 8);          \
        bf[SLOT][3] = *reinterpret_cast<const s16x8*>(tp_ + 3 * 64 * 8);          \
    }

    S3_LOAD(0, 0)
    S3_LOAD(1, 1)

    #pragma unroll
    for (int t = 0; t < 4; ++t) {
        const int slot = t % 3;
        if (t + 2 < 4) { const int ns = (t + 2) % 3; S3_LOAD(t + 2, ns) }
        #pragma unroll
        for (int mi = 0; mi < 2; ++mi)
            #pragma unroll
            for (int ni = 0; ni < 4; ++ni)
                acc[mi][ni] = __builtin_amdgcn_mfma_f32_16x16x32_bf16(
                    af[slot][mi], bf[slot][ni], acc[mi][ni], 0, 0, 0);
    }
#undef S3_LOAD

    // D[row=c_local][col=l_local]; f32x4 regs span 4 consecutive c.
    const int c0 = cb * 128 + w * 32 + (lane >> 4) * 4;
    const int l0 = lb * 64 + (lane & 15);
    #pragma unroll
    for (int mi = 0; mi < 2; ++mi)
        #pragma unroll
        for (int ni = 0; ni < 4; ++ni) {
            float* op = out + ((size_t)b * LN + l0 + ni * 16) * NC + c0 + mi * 16;
            __builtin_nontemporal_store(acc[mi][ni], reinterpret_cast<f32x4*>(op));
        }
}

extern "C" void kernel_launch(void* const* d_in, const int* in_sizes, int n_in,
                              void* d_out, int out_size, void* d_ws, size_t ws_size,
                              hipStream_t stream) {
    const float* q  = (const float*)d_in[0];
    // d_in[1] (k) and d_in[2] (v) are unused by the reference
    const float* w1 = (const float*)d_in[3];
    const float* w2 = (const float*)d_in[4];
    float* out = (float*)d_out;
    float* ws  = (float*)d_ws;

    unsigned short* tfp = (unsigned short*)(ws + WS_TF);
    unsigned short* gf  = (unsigned short*)(ws + WS_GF);
    float*          xp  = ws + WS_XP;
    float*          xs  = ws + WS_XS;

    k_fs1<<<dim3(8, NH, NB), 256, 0, stream>>>(q, xp);
    k_presum<<<768, 256, 0, stream>>>(xp, xs, tfp);
    k_s2<<<256, 256, 0, stream>>>(w1, w2, xs, gf);
    k_s3<<<dim3(64, 4, NB), 256, 0, stream>>>(gf, tfp, out);
}

// Round 16
// 50.770 us; speedup vs baseline: 2.7211x; 1.0617x over previous
//
#include <hip/hip_runtime.h>
#include <hip/hip_bf16.h>
#include <math.h>

// Problem constants
#define NB 8
#define LN 4096       // sequence length L
#define NH 8
#define NE 64
#define NC 512        // NH*NE channels
#define NM 64         // modes kept
#define LMASK 4095

typedef short s16x8 __attribute__((ext_vector_type(8)));
typedef float f32x4 __attribute__((ext_vector_type(4)));
typedef const __attribute__((address_space(1))) void gv_t;
typedef __attribute__((address_space(3))) void lv_t;

// ws layout (in floats):
//  tf  : bf16[4kk][256lt][64][8]        @ 262144   (1 MB)  inv twiddle B-fragments
//  gf  : bf16[8b][4kk][32ct][64][8]     @ 524288   (1 MB)  mixed-spectrum A-fragments
//  xp  : f32[8ks][8b][8h][64i][128m±]   @ 786432   (16 MB) partial fwd GEMM outputs
//  xs  : f32[8b][8h][64i][128m±]        @ 4980736  (2 MB)  ks-summed spectrum
#define WS_TF  262144
#define WS_GF  524288
#define WS_XP  786432
#define WS_XS  4980736

static __device__ __forceinline__ unsigned short bf16bits(float f) {
    __hip_bfloat16 b = __float2bfloat16(f);
    return *reinterpret_cast<unsigned short*>(&b);
}

// Fused stage 1 (v9 = v8 + 3 blocks/CU + setprio around MFMA cluster).
// grid (8 ks, 8 h, 8 b), 256 thr = 4 waves. LDS 48 KB -> 3 blocks/CU (144/160 KB),
// raising in-flight q-DMA per CU to ~48 KB (≈13.6 TB/s sustainable vs 6.9 needed)
// and giving the scheduler a third block to run while others sit at barriers.
// egf computed in-kernel (2-slot ring); q staged via 4-slot depth-3 DMA ring.
__global__ __launch_bounds__(256, 3) void k_fs1(const float* __restrict__ q,
                                                float* __restrict__ xp) {
    __shared__ float qlds[4][4][32][16];        // 32 KB: [slot][wave][l][i]
    __shared__ unsigned short eglds[2][4096];   // 16 KB: [slot][one kc's fragments]
    const int ks = blockIdx.x, h = blockIdx.y, b = blockIdx.z;
    const int tid = threadIdx.x;
    const int w = tid >> 6, lane = tid & 63;
    const int g = lane >> 4, r = lane & 15;

    const float* qsrc = q + (((size_t)b * LN + ks * 512 + (lane >> 2)) * NH + h) * NE
                          + w * 16 + (lane & 3) * 4;

    // Twiddle-generation constants: thread tid covers eglds shorts [tid*16, tid*16+16):
    // group e<8: cos rows (mpm even); group e>=8: -sin rows (mpm odd); same angles.
    const int m_tw  = (tid >> 5) * 8 + (tid & 7);   // mode m (both groups)
    const int kg_tw = (tid >> 3) & 3;               // l-octet within the 32-l tile

#define STAGE_Q(T) { \
    __builtin_amdgcn_global_load_lds((gv_t*)(qsrc + (size_t)(T) * 32 * NC), \
        (lv_t*)(&qlds[(T) & 3][w][0][0]), 16, 0, 0); \
    __builtin_amdgcn_global_load_lds((gv_t*)(qsrc + ((size_t)(T) * 32 + 16) * NC), \
        (lv_t*)(&qlds[(T) & 3][w][16][0]), 16, 0, 0); }

    f32x4 acc[8];
    #pragma unroll
    for (int mt = 0; mt < 8; ++mt) acc[mt] = (f32x4)(0.0f);

    STAGE_Q(0) STAGE_Q(1) STAGE_Q(2)

    #pragma unroll
    for (int t = 0; t < 16; ++t) {
        // ---- generate egf tile t (kc = ks*16 + t) into eglds[t&1] ----
        {
            const int kc = ks * 16 + t;
            int tw = (m_tw * (kc * 32 + kg_tw * 8)) & LMASK;
            unsigned short vc[8], vs[8];
            #pragma unroll
            for (int j = 0; j < 8; ++j) {
                float ang = (6.283185307179586f / 4096.0f) * (float)tw;
                vc[j] = bf16bits(__cosf(ang));
                vs[j] = bf16bits(-__sinf(ang));
                tw = (tw + m_tw) & LMASK;
            }
            uint4 p0, p1;
            p0.x = (unsigned)vc[0] | ((unsigned)vc[1] << 16);
            p0.y = (unsigned)vc[2] | ((unsigned)vc[3] << 16);
            p0.z = (unsigned)vc[4] | ((unsigned)vc[5] << 16);
            p0.w = (unsigned)vc[6] | ((unsigned)vc[7] << 16);
            p1.x = (unsigned)vs[0] | ((unsigned)vs[1] << 16);
            p1.y = (unsigned)vs[2] | ((unsigned)vs[3] << 16);
            p1.z = (unsigned)vs[4] | ((unsigned)vs[5] << 16);
            p1.w = (unsigned)vs[6] | ((unsigned)vs[7] << 16);
            *reinterpret_cast<uint4*>(&eglds[t & 1][tid * 16])     = p0;
            *reinterpret_cast<uint4*>(&eglds[t & 1][tid * 16 + 8]) = p1;
        }
        // q-only vmcnt: keep {q(t+1), q(t+2)} = 4 ops in flight; drain the tail.
        if (t <= 13)      asm volatile("s_waitcnt vmcnt(4)" ::: "memory");
        else if (t == 14) asm volatile("s_waitcnt vmcnt(2)" ::: "memory");
        else              asm volatile("s_waitcnt vmcnt(0)" ::: "memory");
        asm volatile("s_waitcnt lgkmcnt(0)" ::: "memory");   // eglds writes visible
        __builtin_amdgcn_s_barrier();                         // raw: no vmcnt drain
        asm volatile("" ::: "memory");
        if (t + 3 < 16) STAGE_Q(t + 3)

        // A fragments from the in-LDS twiddle tile
        s16x8 af[8];
        #pragma unroll
        for (int mt = 0; mt < 8; ++mt)
            af[mt] = *reinterpret_cast<const s16x8*>(&eglds[t & 1][mt * 512 + lane * 8]);
        // B fragment: f32 gather from own wave's staged subtile, RNE cvt (unchanged)
        s16x8 bfr;
        #pragma unroll
        for (int j = 0; j < 8; ++j)
            bfr[j] = (short)bf16bits(qlds[t & 3][w][g * 8 + j][r]);

        __builtin_amdgcn_s_setprio(1);       // T5: favor MFMA-entering waves
        #pragma unroll
        for (int mt = 0; mt < 8; ++mt)
            acc[mt] = __builtin_amdgcn_mfma_f32_16x16x32_bf16(af[mt], bfr, acc[mt], 0, 0, 0);
        __builtin_amdgcn_s_setprio(0);
    }
#undef STAGE_Q

    // Epilogue: D row = m±-local = (lane>>4)*4 + reg, col = i-local = lane&15.
    const int i = w * 16 + r;
    float* xpb = xp + ((size_t)ks * 64 + b * 8 + h) * (64 * 128) + (size_t)i * 128 + g * 4;
    #pragma unroll
    for (int mt = 0; mt < 8; ++mt)
        *reinterpret_cast<f32x4*>(xpb + mt * 16) = acc[mt];
}

// presum (blocks 0..511) + tf generation (blocks 512..767).
__global__ __launch_bounds__(256) void k_presum(const float* __restrict__ xp,
                                                float* __restrict__ xs,
                                                unsigned short* __restrict__ tfp) {
    const int bid = blockIdx.x;
    if (bid < 512) {
        int e4 = bid * 256 + threadIdx.x;     // 0..131071 float4s
        const f32x4* xp4 = reinterpret_cast<const f32x4*>(xp);
        f32x4 s = (f32x4)(0.0f);
        #pragma unroll
        for (int ks = 0; ks < 8; ++ks)
            s += __builtin_nontemporal_load(&xp4[(size_t)ks * 131072 + e4]);
        reinterpret_cast<f32x4*>(xs)[e4] = s;
        return;
    }
    // tf: T[l][2m]=cos, T[l][2m+1]=sin ; slot s=(kk<<14)|(lt<<6)|lane
    const int s = (bid - 512) * 256 + threadIdx.x;   // 0..65535
    const int lane = s & 63;
    const int lt = (s >> 6) & 255, kk = s >> 14;
    const int l = lt * 16 + (lane & 15);
    const int khi = (lane >> 4) * 8;
    unsigned short v[8];
    #pragma unroll
    for (int j = 0; j < 8; ++j) {
        int mp = kk * 32 + khi + j;
        int m = mp >> 1;
        int tw = (m * l) & LMASK;
        float ang = (6.283185307179586f / 4096.0f) * (float)tw;
        v[j] = bf16bits((mp & 1) ? sinf(ang) : cosf(ang));
    }
    uint4 pk;
    pk.x = (unsigned)v[0] | ((unsigned)v[1] << 16);
    pk.y = (unsigned)v[2] | ((unsigned)v[3] << 16);
    pk.z = (unsigned)v[4] | ((unsigned)v[5] << 16);
    pk.w = (unsigned)v[6] | ((unsigned)v[7] << 16);
    *reinterpret_cast<uint4*>(tfp + (size_t)s * 8) = pk;
}

// Stage 2 (round-14 proven: LDS-staged, unroll-8 w-stream, w1/w2 read once).
__global__ __launch_bounds__(256) void k_s2(const float* __restrict__ w1,
                                            const float* __restrict__ w2,
                                            const float* __restrict__ xs,
                                            unsigned short* __restrict__ gf) {
    __shared__ float2 sxs[2][64][64];    // [bsub][i][m] = 64 KB
    const int sid = blockIdx.x;
    const int x   = sid & 7;
    const int idx = sid >> 3;
    const int r   = x * 8 + (idx & 7);   // (og,h) index
    const int og  = r >> 3, h = r & 7;
    const int bb  = idx >> 3;            // 0..3
    const int tt  = threadIdx.x;

    {
        float4* dst = reinterpret_cast<float4*>(&sxs[0][0][0]);
        #pragma unroll
        for (int bs = 0; bs < 2; ++bs) {
            const float4* s4 = reinterpret_cast<const float4*>(
                xs + ((size_t)((bb * 2 + bs) * 8 + h)) * 8192);
            #pragma unroll
            for (int k = 0; k < 8; ++k)
                dst[bs * 2048 + k * 256 + tt] = s4[k * 256 + tt];
        }
    }
    __syncthreads();

    const int m    = tt & 63;
    const int osub = tt >> 6;            // 0..3
    const int o0   = og * 8 + osub * 2;  // 2 o per thread

    float re[2][2], im[2][2];            // [oo][bs]
    #pragma unroll
    for (int oo = 0; oo < 2; ++oo)
        #pragma unroll
        for (int bs = 0; bs < 2; ++bs) { re[oo][bs] = 0.f; im[oo][bs] = 0.f; }

    const float* w1p = w1 + (size_t)h * (NE * NE * NM) + (size_t)o0 * NM + m;
    const float* w2p = w2 + (size_t)h * (NE * NE * NM) + (size_t)o0 * NM + m;

    #pragma unroll 8
    for (int i = 0; i < NE; ++i) {
        float wr0 = w1p[(size_t)i * (NE * NM)];
        float wi0 = w2p[(size_t)i * (NE * NM)];
        float wr1 = w1p[(size_t)i * (NE * NM) + NM];
        float wi1 = w2p[(size_t)i * (NE * NM) + NM];
        #pragma unroll
        for (int bs = 0; bs < 2; ++bs) {
            float2 xv = sxs[bs][i][m];
            re[0][bs] = fmaf(xv.x, wr0, fmaf(-xv.y, wi0, re[0][bs]));
            im[0][bs] = fmaf(xv.x, wi0, fmaf( xv.y, wr0, im[0][bs]));
            re[1][bs] = fmaf(xv.x, wr1, fmaf(-xv.y, wi1, re[1][bs]));
            im[1][bs] = fmaf(xv.x, wi1, fmaf( xv.y, wr1, im[1][bs]));
        }
    }

    const float sca = (m == 0 ? 1.0f : 2.0f) / (float)LN;  // (2-delta_m0)/L fold
    // G[2m][c]=s*re, G[2m+1][c]=-s*im into A-fragment layout:
    // slot = ((b*4 + (m>>4))*32 + (c>>4))*64 + ((m&15)>>2)*16 + (c&15), elems ((m&3)<<1)+{0,1}
    const int kk  = m >> 4;
    const int khi = ((m & 15) >> 2) * 16;
    const int jj  = (m & 3) << 1;
    #pragma unroll
    for (int oo = 0; oo < 2; ++oo) {
        const int c = h * 64 + o0 + oo;
        #pragma unroll
        for (int bs = 0; bs < 2; ++bs) {
            const int b = bb * 2 + bs;
            size_t slot = (((size_t)b * 4 + kk) * 32 + (c >> 4)) * 64 + khi + (c & 15);
            unsigned int pk = (unsigned)bf16bits(re[oo][bs] * sca) |
                              ((unsigned)bf16bits(-im[oo][bs] * sca) << 16);
            *reinterpret_cast<unsigned int*>(gf + slot * 8 + jj) = pk;
        }
    }
}

// Stage 3 MFMA (round-14 proven, NT stores; + setprio around MFMA quads —
// barrier-free kernel, waves drift out of phase -> T5's precondition holds).
__global__ __launch_bounds__(256, 2) void k_s3(const unsigned short* __restrict__ gf,
                                               const unsigned short* __restrict__ tfp,
                                               float* __restrict__ out) {
    const int lb = blockIdx.x;   // l base = lb*64
    const int cb = blockIdx.y;   // c base = cb*128
    const int b  = blockIdx.z;
    const int tid = threadIdx.x;
    const int w = tid >> 6, lane = tid & 63;

    const unsigned short* ga = gf + ((((size_t)b * 4) * 32 + cb * 8 + w * 2) * 64 + lane) * 8;
    const unsigned short* tb = tfp + (((size_t)lb * 4) * 64 + lane) * 8;

    f32x4 acc[2][4] = {};
    s16x8 af[3][2], bf[3][4];

#define S3_LOAD(T, SLOT)                                                          \
    {                                                                             \
        const unsigned short* gp_ = ga + (size_t)(T) * (32 * 64 * 8);             \
        const unsigned short* tp_ = tb + (size_t)(T) * (256 * 64 * 8);            \
        af[SLOT][0] = *reinterpret_cast<const s16x8*>(gp_);                       \
        af[SLOT][1] = *reinterpret_cast<const s16x8*>(gp_ + 64 * 8);              \
        bf[SLOT][0] = *reinterpret_cast<const s16x8*>(tp_);                       \
        bf[SLOT][1] = *reinterpret_cast<const s16x8*>(tp_ + 64 * 8);              \
        bf[SLOT][2] = *reinterpret_cast<const s16x8*>(tp_ + 2 * 64 * 8);          \
        bf[SLOT][3] = *reinterpret_cast<const s16x8*>(tp_ + 3 * 64 * 8);          \
    }

    S3_LOAD(0, 0)
    S3_LOAD(1, 1)

    #pragma unroll
    for (int t = 0; t < 4; ++t) {
        const int slot = t % 3;
        if (t + 2 < 4) { const int ns = (t + 2) % 3; S3_LOAD(t + 2, ns) }
        __builtin_amdgcn_s_setprio(1);
        #pragma unroll
        for (int mi = 0; mi < 2; ++mi)
            #pragma unroll
            for (int ni = 0; ni < 4; ++ni)
                acc[mi][ni] = __builtin_amdgcn_mfma_f32_16x16x32_bf16(
                    af[slot][mi], bf[slot][ni], acc[mi][ni], 0, 0, 0);
        __builtin_amdgcn_s_setprio(0);
    }
#undef S3_LOAD

    // D[row=c_local][col=l_local]; f32x4 regs span 4 consecutive c.
    const int c0 = cb * 128 + w * 32 + (lane >> 4) * 4;
    const int l0 = lb * 64 + (lane & 15);
    #pragma unroll
    for (int mi = 0; mi < 2; ++mi)
        #pragma unroll
        for (int ni = 0; ni < 4; ++ni) {
            float* op = out + ((size_t)b * LN + l0 + ni * 16) * NC + c0 + mi * 16;
            __builtin_nontemporal_store(acc[mi][ni], reinterpret_cast<f32x4*>(op));
        }
}

extern "C" void kernel_launch(void* const* d_in, const int* in_sizes, int n_in,
                              void* d_out, int out_size, void* d_ws, size_t ws_size,
                              hipStream_t stream) {
    const float* q  = (const float*)d_in[0];
    // d_in[1] (k) and d_in[2] (v) are unused by the reference
    const float* w1 = (const float*)d_in[3];
    const float* w2 = (const float*)d_in[4];
    float* out = (float*)d_out;
    float* ws  = (float*)d_ws;

    unsigned short* tfp = (unsigned short*)(ws + WS_TF);
    unsigned short* gf  = (unsigned short*)(ws + WS_GF);
    float*          xp  = ws + WS_XP;
    float*          xs  = ws + WS_XS;

    k_fs1<<<dim3(8, NH, NB), 256, 0, stream>>>(q, xp);
    k_presum<<<768, 256, 0, stream>>>(xp, xs, tfp);
    k_s2<<<256, 256, 0, stream>>>(w1, w2, xs, gf);
    k_s3<<<dim3(64, 4, NB), 256, 0, stream>>>(gf, tfp, out);
}

// Round 17
// 50.225 us; speedup vs baseline: 2.7507x; 1.0109x over previous
//
#include <hip/hip_runtime.h>
#include <hip/hip_bf16.h>
#include <math.h>

// Problem constants
#define NB 8
#define LN 4096       // sequence length L
#define NH 8
#define NE 64
#define NC 512        // NH*NE channels
#define NM 64         // modes kept
#define LMASK 4095

typedef short s16x8 __attribute__((ext_vector_type(8)));
typedef float f32x4 __attribute__((ext_vector_type(4)));
typedef const __attribute__((address_space(1))) void gv_t;
typedef __attribute__((address_space(3))) void lv_t;

// ws layout (in floats):
//  tf  : bf16[4kk][256lt][64][8]        @ 262144   (1 MB)  inv twiddle B-fragments
//  gf  : bf16[8b][4kk][32ct][64][8]     @ 524288   (1 MB)  mixed-spectrum A-fragments
//  xp  : f32[8ks][8b][8h][64i][128m±]   @ 786432   (16 MB) partial fwd GEMM outputs
#define WS_TF  262144
#define WS_GF  524288
#define WS_XP  786432

static __device__ __forceinline__ unsigned short bf16bits(float f) {
    __hip_bfloat16 b = __float2bfloat16(f);
    return *reinterpret_cast<unsigned short*>(&b);
}

// Fused stage 1 (v9, round-16 proven: 3 blocks/CU, in-kernel egf, setprio).
// grid (8 ks, 8 h, 8 b), 256 thr = 4 waves. LDS 48 KB -> 3 blocks/CU.
__global__ __launch_bounds__(256, 3) void k_fs1(const float* __restrict__ q,
                                                float* __restrict__ xp) {
    __shared__ float qlds[4][4][32][16];        // 32 KB: [slot][wave][l][i]
    __shared__ unsigned short eglds[2][4096];   // 16 KB: [slot][one kc's fragments]
    const int ks = blockIdx.x, h = blockIdx.y, b = blockIdx.z;
    const int tid = threadIdx.x;
    const int w = tid >> 6, lane = tid & 63;
    const int g = lane >> 4, r = lane & 15;

    const float* qsrc = q + (((size_t)b * LN + ks * 512 + (lane >> 2)) * NH + h) * NE
                          + w * 16 + (lane & 3) * 4;

    // Twiddle-generation constants: thread tid covers eglds shorts [tid*16, tid*16+16):
    // group e<8: cos rows (mpm even); group e>=8: -sin rows (mpm odd); same angles.
    const int m_tw  = (tid >> 5) * 8 + (tid & 7);   // mode m (both groups)
    const int kg_tw = (tid >> 3) & 3;               // l-octet within the 32-l tile

#define STAGE_Q(T) { \
    __builtin_amdgcn_global_load_lds((gv_t*)(qsrc + (size_t)(T) * 32 * NC), \
        (lv_t*)(&qlds[(T) & 3][w][0][0]), 16, 0, 0); \
    __builtin_amdgcn_global_load_lds((gv_t*)(qsrc + ((size_t)(T) * 32 + 16) * NC), \
        (lv_t*)(&qlds[(T) & 3][w][16][0]), 16, 0, 0); }

    f32x4 acc[8];
    #pragma unroll
    for (int mt = 0; mt < 8; ++mt) acc[mt] = (f32x4)(0.0f);

    STAGE_Q(0) STAGE_Q(1) STAGE_Q(2)

    #pragma unroll
    for (int t = 0; t < 16; ++t) {
        // ---- generate egf tile t (kc = ks*16 + t) into eglds[t&1] ----
        {
            const int kc = ks * 16 + t;
            int tw = (m_tw * (kc * 32 + kg_tw * 8)) & LMASK;
            unsigned short vc[8], vs[8];
            #pragma unroll
            for (int j = 0; j < 8; ++j) {
                float ang = (6.283185307179586f / 4096.0f) * (float)tw;
                vc[j] = bf16bits(__cosf(ang));
                vs[j] = bf16bits(-__sinf(ang));
                tw = (tw + m_tw) & LMASK;
            }
            uint4 p0, p1;
            p0.x = (unsigned)vc[0] | ((unsigned)vc[1] << 16);
            p0.y = (unsigned)vc[2] | ((unsigned)vc[3] << 16);
            p0.z = (unsigned)vc[4] | ((unsigned)vc[5] << 16);
            p0.w = (unsigned)vc[6] | ((unsigned)vc[7] << 16);
            p1.x = (unsigned)vs[0] | ((unsigned)vs[1] << 16);
            p1.y = (unsigned)vs[2] | ((unsigned)vs[3] << 16);
            p1.z = (unsigned)vs[4] | ((unsigned)vs[5] << 16);
            p1.w = (unsigned)vs[6] | ((unsigned)vs[7] << 16);
            *reinterpret_cast<uint4*>(&eglds[t & 1][tid * 16])     = p0;
            *reinterpret_cast<uint4*>(&eglds[t & 1][tid * 16 + 8]) = p1;
        }
        // q-only vmcnt: keep {q(t+1), q(t+2)} = 4 ops in flight; drain the tail.
        if (t <= 13)      asm volatile("s_waitcnt vmcnt(4)" ::: "memory");
        else if (t == 14) asm volatile("s_waitcnt vmcnt(2)" ::: "memory");
        else              asm volatile("s_waitcnt vmcnt(0)" ::: "memory");
        asm volatile("s_waitcnt lgkmcnt(0)" ::: "memory");   // eglds writes visible
        __builtin_amdgcn_s_barrier();                         // raw: no vmcnt drain
        asm volatile("" ::: "memory");
        if (t + 3 < 16) STAGE_Q(t + 3)

        // A fragments from the in-LDS twiddle tile
        s16x8 af[8];
        #pragma unroll
        for (int mt = 0; mt < 8; ++mt)
            af[mt] = *reinterpret_cast<const s16x8*>(&eglds[t & 1][mt * 512 + lane * 8]);
        // B fragment: f32 gather from own wave's staged subtile, RNE cvt (unchanged)
        s16x8 bfr;
        #pragma unroll
        for (int j = 0; j < 8; ++j)
            bfr[j] = (short)bf16bits(qlds[t & 3][w][g * 8 + j][r]);

        __builtin_amdgcn_s_setprio(1);       // T5: favor MFMA-entering waves
        #pragma unroll
        for (int mt = 0; mt < 8; ++mt)
            acc[mt] = __builtin_amdgcn_mfma_f32_16x16x32_bf16(af[mt], bfr, acc[mt], 0, 0, 0);
        __builtin_amdgcn_s_setprio(0);
    }
#undef STAGE_Q

    // Epilogue: D row = m±-local = (lane>>4)*4 + reg, col = i-local = lane&15.
    const int i = w * 16 + r;
    float* xpb = xp + ((size_t)ks * 64 + b * 8 + h) * (64 * 128) + (size_t)i * 128 + g * 4;
    #pragma unroll
    for (int mt = 0; mt < 8; ++mt)
        *reinterpret_cast<f32x4*>(xpb + mt * 16) = acc[mt];
}

// Stage 2 (v4): presum FOLDED INTO the staging loop — the block sums the 8 xp
// partials directly into LDS (same ks-ascending f32x4 order as the old presum ->
// bit-exact). Block map og=bid>>5, bb=(bid>>3)&3, h=bid&7: bid%8 = h, so ALL 32
// blocks sharing an h land on one XCD; that h-slice's working set (w 2MB + xp
// 2MB) fits the 4MB per-XCD L2 -> w and xp each stream from HBM once per XCD.
// Blocks 256..511 generate tf (unchanged precise-trig values). xs is deleted.
__global__ __launch_bounds__(256) void k_s2(const float* __restrict__ w1,
                                            const float* __restrict__ w2,
                                            const float* __restrict__ xp,
                                            unsigned short* __restrict__ gf,
                                            unsigned short* __restrict__ tfp) {
    __shared__ float2 sxs[2][64][64];    // [bsub][i][m] = 64 KB
    const int bid = blockIdx.x;
    if (bid >= 256) {
        // tf: T[l][2m]=cos, T[l][2m+1]=sin ; slot s=(kk<<14)|(lt<<6)|lane
        const int s = (bid - 256) * 256 + threadIdx.x;   // 0..65535
        const int lane = s & 63;
        const int lt = (s >> 6) & 255, kk = s >> 14;
        const int l = lt * 16 + (lane & 15);
        const int khi = (lane >> 4) * 8;
        unsigned short v[8];
        #pragma unroll
        for (int j = 0; j < 8; ++j) {
            int mp = kk * 32 + khi + j;
            int m = mp >> 1;
            int tw = (m * l) & LMASK;
            float ang = (6.283185307179586f / 4096.0f) * (float)tw;
            v[j] = bf16bits((mp & 1) ? sinf(ang) : cosf(ang));
        }
        uint4 pk;
        pk.x = (unsigned)v[0] | ((unsigned)v[1] << 16);
        pk.y = (unsigned)v[2] | ((unsigned)v[3] << 16);
        pk.z = (unsigned)v[4] | ((unsigned)v[5] << 16);
        pk.w = (unsigned)v[6] | ((unsigned)v[7] << 16);
        *reinterpret_cast<uint4*>(tfp + (size_t)s * 8) = pk;
        return;
    }

    const int og = bid >> 5;             // 0..7
    const int bb = (bid >> 3) & 3;       // 0..3
    const int h  = bid & 7;              // 0..7  (== bid%8 -> XCD residence)
    const int tt = threadIdx.x;

    // stage-and-presum: sxs[bs] = sum_ks xp[ks][(bb*2+bs)*8+h]  (ks ascending)
    {
        f32x4* dst = reinterpret_cast<f32x4*>(&sxs[0][0][0]);
        const f32x4* xp4 = reinterpret_cast<const f32x4*>(xp);
        #pragma unroll
        for (int bs = 0; bs < 2; ++bs) {
            const size_t base = (size_t)((bb * 2 + bs) * 8 + h) * 2048;
            #pragma unroll
            for (int k = 0; k < 8; ++k) {
                f32x4 s = (f32x4)(0.0f);
                #pragma unroll
                for (int ks = 0; ks < 8; ++ks)
                    s += __builtin_nontemporal_load(
                        &xp4[(size_t)ks * 131072 + base + k * 256 + tt]);
                dst[bs * 2048 + k * 256 + tt] = s;
            }
        }
    }
    __syncthreads();

    const int m    = tt & 63;
    const int osub = tt >> 6;            // 0..3
    const int o0   = og * 8 + osub * 2;  // 2 o per thread

    float re[2][2], im[2][2];            // [oo][bs]
    #pragma unroll
    for (int oo = 0; oo < 2; ++oo)
        #pragma unroll
        for (int bs = 0; bs < 2; ++bs) { re[oo][bs] = 0.f; im[oo][bs] = 0.f; }

    const float* w1p = w1 + (size_t)h * (NE * NE * NM) + (size_t)o0 * NM + m;
    const float* w2p = w2 + (size_t)h * (NE * NE * NM) + (size_t)o0 * NM + m;

    #pragma unroll 8
    for (int i = 0; i < NE; ++i) {
        float wr0 = w1p[(size_t)i * (NE * NM)];
        float wi0 = w2p[(size_t)i * (NE * NM)];
        float wr1 = w1p[(size_t)i * (NE * NM) + NM];
        float wi1 = w2p[(size_t)i * (NE * NM) + NM];
        #pragma unroll
        for (int bs = 0; bs < 2; ++bs) {
            float2 xv = sxs[bs][i][m];
            re[0][bs] = fmaf(xv.x, wr0, fmaf(-xv.y, wi0, re[0][bs]));
            im[0][bs] = fmaf(xv.x, wi0, fmaf( xv.y, wr0, im[0][bs]));
            re[1][bs] = fmaf(xv.x, wr1, fmaf(-xv.y, wi1, re[1][bs]));
            im[1][bs] = fmaf(xv.x, wi1, fmaf( xv.y, wr1, im[1][bs]));
        }
    }

    const float sca = (m == 0 ? 1.0f : 2.0f) / (float)LN;  // (2-delta_m0)/L fold
    // G[2m][c]=s*re, G[2m+1][c]=-s*im into A-fragment layout:
    // slot = ((b*4 + (m>>4))*32 + (c>>4))*64 + ((m&15)>>2)*16 + (c&15), elems ((m&3)<<1)+{0,1}
    const int kk  = m >> 4;
    const int khi = ((m & 15) >> 2) * 16;
    const int jj  = (m & 3) << 1;
    #pragma unroll
    for (int oo = 0; oo < 2; ++oo) {
        const int c = h * 64 + o0 + oo;
        #pragma unroll
        for (int bs = 0; bs < 2; ++bs) {
            const int b = bb * 2 + bs;
            size_t slot = (((size_t)b * 4 + kk) * 32 + (c >> 4)) * 64 + khi + (c & 15);
            unsigned int pk = (unsigned)bf16bits(re[oo][bs] * sca) |
                              ((unsigned)bf16bits(-im[oo][bs] * sca) << 16);
            *reinterpret_cast<unsigned int*>(gf + slot * 8 + jj) = pk;
        }
    }
}

// Stage 3 MFMA (round-16 proven: NT stores + setprio; near write-floor).
__global__ __launch_bounds__(256, 2) void k_s3(const unsigned short* __restrict__ gf,
                                               const unsigned short* __restrict__ tfp,
                                               float* __restrict__ out) {
    const int lb = blockIdx.x;   // l base = lb*64
    const int cb = blockIdx.y;   // c base = cb*128
    const int b  = blockIdx.z;
    const int tid = threadIdx.x;
    const int w = tid >> 6, lane = tid & 63;

    const unsigned short* ga = gf + ((((size_t)b * 4) * 32 + cb * 8 + w * 2) * 64 + lane) * 8;
    const unsigned short* tb = tfp + (((size_t)lb * 4) * 64 + lane) * 8;

    f32x4 acc[2][4] = {};
    s16x8 af[3][2], bf[3][4];

#define S3_LOAD(T, SLOT)                                                          \
    {                                                                             \
        const unsigned short* gp_ = ga + (size_t)(T) * (32 * 64 * 8);             \
        const unsigned short* tp_ = tb + (size_t)(T) * (256 * 64 * 8);            \
        af[SLOT][0] = *reinterpret_cast<const s16x8*>(gp_);                       \
        af[SLOT][1] = *reinterpret_cast<const s16x8*>(gp_ + 64 * 8);              \
        bf[SLOT][0] = *reinterpret_cast<const s16x8*>(tp_);                       \
        bf[SLOT][1] = *reinterpret_cast<const s16x8*>(tp_ + 64 * 8);              \
        bf[SLOT][2] = *reinterpret_cast<const s16x8*>(tp_ + 2 * 64 * 8);          \
        bf[SLOT][3] = *reinterpret_cast<const s16x8*>(tp_ + 3 * 64 * 8);          \
    }

    S3_LOAD(0, 0)
    S3_LOAD(1, 1)

    #pragma unroll
    for (int t = 0; t < 4; ++t) {
        const int slot = t % 3;
        if (t + 2 < 4) { const int ns = (t + 2) % 3; S3_LOAD(t + 2, ns) }
        __builtin_amdgcn_s_setprio(1);
        #pragma unroll
        for (int mi = 0; mi < 2; ++mi)
            #pragma unroll
            for (int ni = 0; ni < 4; ++ni)
                acc[mi][ni] = __builtin_amdgcn_mfma_f32_16x16x32_bf16(
                    af[slot][mi], bf[slot][ni], acc[mi][ni], 0, 0, 0);
        __builtin_amdgcn_s_setprio(0);
    }
#undef S3_LOAD

    // D[row=c_local][col=l_local]; f32x4 regs span 4 consecutive c.
    const int c0 = cb * 128 + w * 32 + (lane >> 4) * 4;
    const int l0 = lb * 64 + (lane & 15);
    #pragma unroll
    for (int mi = 0; mi < 2; ++mi)
        #pragma unroll
        for (int ni = 0; ni < 4; ++ni) {
            float* op = out + ((size_t)b * LN + l0 + ni * 16) * NC + c0 + mi * 16;
            __builtin_nontemporal_store(acc[mi][ni], reinterpret_cast<f32x4*>(op));
        }
}

extern "C" void kernel_launch(void* const* d_in, const int* in_sizes, int n_in,
                              void* d_out, int out_size, void* d_ws, size_t ws_size,
                              hipStream_t stream) {
    const float* q  = (const float*)d_in[0];
    // d_in[1] (k) and d_in[2] (v) are unused by the reference
    const float* w1 = (const float*)d_in[3];
    const float* w2 = (const float*)d_in[4];
    float* out = (float*)d_out;
    float* ws  = (float*)d_ws;

    unsigned short* tfp = (unsigned short*)(ws + WS_TF);
    unsigned short* gf  = (unsigned short*)(ws + WS_GF);
    float*          xp  = ws + WS_XP;

    k_fs1<<<dim3(8, NH, NB), 256, 0, stream>>>(q, xp);
    k_s2<<<512, 256, 0, stream>>>(w1, w2, xp, gf, tfp);
    k_s3<<<dim3(64, 4, NB), 256, 0, stream>>>(gf, tfp, out);
}